// Round 1
// baseline (133.931 us; speedup 1.0000x reference)
//
#include <hip/hip_runtime.h>

#define SEQ   1024
#define BATCH 32
#define DIM   256   // 64 float4 per row

typedef float f4 __attribute__((ext_vector_type(4)));

// ---------------------------------------------------------------------------
// Kernel 1: per-batch inclusive scan of durations (1024 tokens, 256 threads x
// 4 tokens each, LDS Hillis-Steele), then a GENERATIVE scatter of the
// frame -> within-token-position map in COLUMN-MAJOR layout pos[b*T + f].
//   - valid frames [0, total[b]) : each token with d>0 writes k=0..d-1 into a
//     contiguous run -> coalesced block-level stores (the old row-major layout
//     had 128B stride => 32x cacheline write amplification).
//   - tail frames [total[b], T)  : filled with -1 here, coalesced, which
//     removes the previous full-array pe_fill kernel (460 KB + a launch).
// Every frame in [0,T) is written exactly once => no reliance on ws poison.
// ---------------------------------------------------------------------------
__global__ __launch_bounds__(256) void pe_scan_scatter(const int* __restrict__ dur,
                                                       int* __restrict__ pos,  // [BATCH][T]
                                                       int T) {
    const int b = blockIdx.x;    // batch element, 0..31
    const int t = threadIdx.x;   // 0..255
    __shared__ int ssum[256];

    // load 4 consecutive tokens for this thread (column b, stride BATCH)
    int d[4];
    const int base = (t * 4) * BATCH + b;
#pragma unroll
    for (int i = 0; i < 4; ++i) d[i] = dur[base + i * BATCH];

    ssum[t] = d[0] + d[1] + d[2] + d[3];
    __syncthreads();

    // Hillis-Steele inclusive scan over the 256 per-thread sums
    for (int off = 1; off < 256; off <<= 1) {
        int v = (t >= off) ? ssum[t - off] : 0;
        __syncthreads();
        ssum[t] += v;
        __syncthreads();
    }

    const int total = ssum[255];            // total frames for this batch, <= T
    int start = (t > 0) ? ssum[t - 1] : 0;  // exclusive prefix for token 4t
    int* __restrict__ prow = pos + b * T;

#pragma unroll
    for (int i = 0; i < 4; ++i) {
        for (int k = 0; k < d[i]; ++k) {    // d[i] in [0, 8); start+k < total <= T
            prow[start + k] = k;
        }
        start += d[i];
    }

    // tail fill (contiguous, ~T - total ~ 100 rows per batch)
    for (int f = total + t; f < T; f += 256) prow[f] = -1;
}

// ---------------------------------------------------------------------------
// Kernel 2: gather. Grid-stride loop at exactly max occupancy
// (2048 blocks x 256 thr = 8192 waves = 32 waves/CU on 256 CUs).
// One 16B float4 per thread per iteration, fully coalesced; within a wave all
// 64 lanes share one row => a single 4B pos request + one L1-hot encoding row
// (only rows 0..7 are ever touched). Output (121 MB) is streamed with
// nontemporal stores: never re-read, so don't let it churn L2.
// ---------------------------------------------------------------------------
__global__ __launch_bounds__(256) void pe_gather(const int* __restrict__ pos,
                                                 const f4* __restrict__ enc,
                                                 f4* __restrict__ out,
                                                 int T, int n4) {
    const int stride = gridDim.x * blockDim.x;
    for (int idx = blockIdx.x * blockDim.x + threadIdx.x; idx < n4; idx += stride) {
        const int row = idx >> 6;        // (frame, batch) output row
        const int c   = idx & 63;        // float4 column within DIM
        const int f   = row >> 5;        // BATCH = 32
        const int b   = row & 31;
        const int p   = pos[b * T + f];  // uniform across the wave's 64 lanes
        f4 v = {0.f, 0.f, 0.f, 0.f};
        if (p >= 0) v = enc[p * (DIM / 4) + c];
        __builtin_nontemporal_store(v, &out[idx]);
    }
}

extern "C" void kernel_launch(void* const* d_in, const int* in_sizes, int n_in,
                              void* d_out, int out_size, void* d_ws, size_t ws_size,
                              hipStream_t stream) {
    const int* dur = (const int*)d_in[0];     // (SEQ, BATCH) int32
    const f4*  enc = (const f4*)d_in[1];      // (1000, DIM) float32
    f4*        out = (f4*)d_out;              // (T, BATCH, DIM) float32

    const int T  = out_size / (BATCH * DIM);  // harness gives flat out elems
    int* pos = (int*)d_ws;                    // [BATCH][T] ints, ~460 KB

    pe_scan_scatter<<<BATCH, 256, 0, stream>>>(dur, pos, T);

    const int n4 = T * BATCH * (DIM / 4);
    // 2048 blocks x 4 waves = 8192 waves = 32 waves/CU: full occupancy,
    // ~14 grid-stride iterations each (amortizes per-block dispatch cost
    // vs the previous 28.8k single-shot micro-blocks).
    pe_gather<<<2048, 256, 0, stream>>>(pos, enc, out, T, n4);
}

// Round 3
// 129.290 us; speedup vs baseline: 1.0359x; 1.0359x over previous
//
#include <hip/hip_runtime.h>

#define SEQ   1024
#define BATCH 32
#define DIM   256   // 64 float4 per row

typedef float f4 __attribute__((ext_vector_type(4)));

// ---------------------------------------------------------------------------
// Kernel 1: per-batch inclusive scan of durations + generative scatter of the
// frame -> within-token-position map, column-major pos[b*T + f].
//
// Scan structure: per-wave __shfl_up inclusive scan of the 64 per-thread sums
// (6 shuffle steps, no barriers), then ONE __syncthreads to combine the 4
// wave totals via LDS (vs the old 8-step Hillis-Steele with 16 barriers).
//
//   - valid frames [0, total[b]) : token t writes k=0..d-1 contiguously
//   - tail frames [total[b], T)  : -1, coalesced
// Every frame in [0,T) written exactly once => no reliance on ws poison.
// ---------------------------------------------------------------------------
__global__ __launch_bounds__(256) void pe_scan_scatter(const int* __restrict__ dur,
                                                       int* __restrict__ pos,  // [BATCH][T]
                                                       int T) {
    const int b    = blockIdx.x;     // batch element, 0..31
    const int t    = threadIdx.x;    // 0..255
    const int lane = t & 63;
    const int w    = t >> 6;         // wave id, 0..3
    __shared__ int wsum[4];

    // load 4 consecutive tokens for this thread (column b, stride BATCH)
    int d[4];
    const int base = (t * 4) * BATCH + b;
#pragma unroll
    for (int i = 0; i < 4; ++i) d[i] = dur[base + i * BATCH];

    const int sum4 = d[0] + d[1] + d[2] + d[3];

    // barrier-free inclusive scan across the wave's 64 per-thread sums
    int s = sum4;
#pragma unroll
    for (int off = 1; off < 64; off <<= 1) {
        int u = __shfl_up(s, off, 64);
        if (lane >= off) s += u;
    }

    if (lane == 63) wsum[w] = s;     // wave total
    __syncthreads();                 // the only barrier in the kernel

    int base_w = 0, total = 0;
#pragma unroll
    for (int i = 0; i < 4; ++i) {
        const int v = wsum[i];       // LDS broadcast, conflict-free
        total += v;
        if (i < w) base_w += v;
    }

    int start = base_w + (s - sum4); // exclusive prefix for token 4t
    int* __restrict__ prow = pos + b * T;

#pragma unroll
    for (int i = 0; i < 4; ++i) {
        for (int k = 0; k < d[i]; ++k) {   // d[i] in [0,8); start+k < total <= T
            prow[start + k] = k;
        }
        start += d[i];
    }

    // tail fill (contiguous, ~T - total rows)
    for (int f = total + t; f < T; f += 256) prow[f] = -1;
}

// ---------------------------------------------------------------------------
// Kernel 2: gather. Grid-stride at exactly max occupancy
// (2048 blocks x 256 thr = 8192 waves = 32 waves/CU on 256 CUs).
// 16B float4 per lane, fully coalesced; all 64 lanes of a wave share one
// output row => one broadcast pos load + one L1-hot encoding row (only rows
// 0..7 ever touched). Plain stores: the 6.3 TB/s reference path
// (fillBuffer) uses plain stores, so match it.
// ---------------------------------------------------------------------------
__global__ __launch_bounds__(256) void pe_gather(const int* __restrict__ pos,
                                                 const f4* __restrict__ enc,
                                                 f4* __restrict__ out,
                                                 int T, int n4) {
    const int stride = gridDim.x * blockDim.x;
    for (int idx = blockIdx.x * blockDim.x + threadIdx.x; idx < n4; idx += stride) {
        const int row = idx >> 6;        // (frame, batch) output row
        const int c   = idx & 63;        // float4 column within DIM
        const int f   = row >> 5;        // BATCH = 32
        const int b   = row & 31;
        const int p   = pos[b * T + f];  // uniform across the wave's 64 lanes
        f4 v = {0.f, 0.f, 0.f, 0.f};
        if (p >= 0) v = enc[p * (DIM / 4) + c];
        out[idx] = v;
    }
}

extern "C" void kernel_launch(void* const* d_in, const int* in_sizes, int n_in,
                              void* d_out, int out_size, void* d_ws, size_t ws_size,
                              hipStream_t stream) {
    const int* dur = (const int*)d_in[0];     // (SEQ, BATCH) int32
    const f4*  enc = (const f4*)d_in[1];      // (1000, DIM) float32
    f4*        out = (f4*)d_out;              // (T, BATCH, DIM) float32

    const int T  = out_size / (BATCH * DIM);  // harness gives flat out elems
    int* pos = (int*)d_ws;                    // [BATCH][T] ints, ~472 KB

    pe_scan_scatter<<<BATCH, 256, 0, stream>>>(dur, pos, T);

    const int n4 = T * BATCH * (DIM / 4);
    pe_gather<<<2048, 256, 0, stream>>>(pos, enc, out, T, n4);
}